// Round 15
// baseline (3578.001 us; speedup 1.0000x reference)
//
#include <hip/hip_runtime.h>

typedef _Float16 half_t;
typedef _Float16 half8 __attribute__((ext_vector_type(8)));
typedef float floatx4 __attribute__((ext_vector_type(4)));

#define NT   300
#define NB   256
#define DIN  512
#define DH   512
#define DOUT 128
#define DX   384        // IN - OUT
#define KZ   896        // folded z GEMM K: 384 (x) + 512 (h1)
#define NG   2048       // 4*DH gate rows
#define NWG  256
#define SMEM 131072     // 64KB ih-slice + 64KB hh-slice per WG
#define RTBLK 32768     // halfs per rt block in blocked activation layout (32*64*16)

#define WAITVM(N) do { asm volatile("s_waitcnt vmcnt(" #N ")" ::: "memory"); \
                       __builtin_amdgcn_sched_barrier(0); } while (0)

// ---------------------------------------------------------------------------
// helpers
// ---------------------------------------------------------------------------

__device__ __forceinline__ float sigm(float x)  { return __builtin_amdgcn_rcpf(1.f + __expf(-x)); }
__device__ __forceinline__ float tanhx(float x) { return 1.f - 2.f * __builtin_amdgcn_rcpf(__expf(2.f * x) + 1.f); }

__device__ __forceinline__ half8 cvt8(const float* s) {
    float4 f0 = *(const float4*)s, f1 = *(const float4*)(s + 4);
    half8 h;
    h[0] = (half_t)f0.x; h[1] = (half_t)f0.y; h[2] = (half_t)f0.z; h[3] = (half_t)f0.w;
    h[4] = (half_t)f1.x; h[5] = (half_t)f1.y; h[6] = (half_t)f1.z; h[7] = (half_t)f1.w;
    return h;
}

// single coherent (LLC) 16B load — caller batches and counts via WAITVM
__device__ __forceinline__ void ldA1(const half_t* a, half8& r) {
    asm volatile("global_load_dwordx4 %0, %1, off sc0 sc1" : "=&v"(r) : "v"(a) : "memory");
}

// coherent batched loads over row-major data (xh), single base + imm offsets
__device__ __forceinline__ void ldA8(const half_t* b, half8& r0, half8& r1, half8& r2, half8& r3,
                                     half8& r4, half8& r5, half8& r6, half8& r7) {
    asm volatile(
        "global_load_dwordx4 %0, %8, off sc0 sc1\n\t"
        "global_load_dwordx4 %1, %8, off offset:64 sc0 sc1\n\t"
        "global_load_dwordx4 %2, %8, off offset:128 sc0 sc1\n\t"
        "global_load_dwordx4 %3, %8, off offset:192 sc0 sc1\n\t"
        "global_load_dwordx4 %4, %8, off offset:256 sc0 sc1\n\t"
        "global_load_dwordx4 %5, %8, off offset:320 sc0 sc1\n\t"
        "global_load_dwordx4 %6, %8, off offset:384 sc0 sc1\n\t"
        "global_load_dwordx4 %7, %8, off offset:448 sc0 sc1"
        : "=&v"(r0), "=&v"(r1), "=&v"(r2), "=&v"(r3),
          "=&v"(r4), "=&v"(r5), "=&v"(r6), "=&v"(r7)
        : "v"(b) : "memory");
}
__device__ __forceinline__ void ldA4(const half_t* b, half8& r0, half8& r1, half8& r2, half8& r3) {
    asm volatile(
        "global_load_dwordx4 %0, %4, off sc0 sc1\n\t"
        "global_load_dwordx4 %1, %4, off offset:64 sc0 sc1\n\t"
        "global_load_dwordx4 %2, %4, off offset:128 sc0 sc1\n\t"
        "global_load_dwordx4 %3, %4, off offset:192 sc0 sc1"
        : "=&v"(r0), "=&v"(r1), "=&v"(r2), "=&v"(r3)
        : "v"(b) : "memory");
}
// cached (L1/L2) batched loads for read-only prepass outputs (W1f)
__device__ __forceinline__ void ldC8(const half_t* b, half8& r0, half8& r1, half8& r2, half8& r3,
                                     half8& r4, half8& r5, half8& r6, half8& r7) {
    asm volatile(
        "global_load_dwordx4 %0, %8, off\n\t"
        "global_load_dwordx4 %1, %8, off offset:64\n\t"
        "global_load_dwordx4 %2, %8, off offset:128\n\t"
        "global_load_dwordx4 %3, %8, off offset:192\n\t"
        "global_load_dwordx4 %4, %8, off offset:256\n\t"
        "global_load_dwordx4 %5, %8, off offset:320\n\t"
        "global_load_dwordx4 %6, %8, off offset:384\n\t"
        "global_load_dwordx4 %7, %8, off offset:448"
        : "=&v"(r0), "=&v"(r1), "=&v"(r2), "=&v"(r3),
          "=&v"(r4), "=&v"(r5), "=&v"(r6), "=&v"(r7)
        : "v"(b) : "memory");
}
__device__ __forceinline__ void ldC4(const half_t* b, half8& r0, half8& r1, half8& r2, half8& r3) {
    asm volatile(
        "global_load_dwordx4 %0, %4, off\n\t"
        "global_load_dwordx4 %1, %4, off offset:64\n\t"
        "global_load_dwordx4 %2, %4, off offset:128\n\t"
        "global_load_dwordx4 %3, %4, off offset:192"
        : "=&v"(r0), "=&v"(r1), "=&v"(r2), "=&v"(r3)
        : "v"(b) : "memory");
}

__device__ __forceinline__ void st_coh_u64(half_t* p, unsigned long long v) {
    asm volatile("global_store_dwordx2 %0, %1, off sc0 sc1" :: "v"(p), "v"(v) : "memory");
}
__device__ __forceinline__ void st_coh_h8(half_t* p, half8 v) {
    asm volatile("global_store_dwordx4 %0, %1, off sc0 sc1" :: "v"(p), "v"(v) : "memory");
}
__device__ __forceinline__ unsigned ld_flag(const unsigned* p) {
    unsigned v;
    asm volatile("global_load_dword %0, %1, off sc0 sc1\n\ts_waitcnt vmcnt(0)"
                 : "=v"(v) : "v"(p) : "memory");
    return v;
}
__device__ __forceinline__ void st_flag(unsigned* p, unsigned v) {
    asm volatile("global_store_dword %0, %1, off sc0 sc1" :: "v"(p), "v"(v) : "memory");
}

// producer WG signals its own slot (after draining its data stores to LLC)
__device__ __forceinline__ void signal_slot(unsigned* sem, int slot, unsigned value) {
    asm volatile("s_waitcnt vmcnt(0) lgkmcnt(0)" ::: "memory");
    __syncthreads();
    if (threadIdx.x == 0) st_flag(sem + (size_t)slot * 16, value);
}
// wait on all 32 producers whose lwg&3 == rt (threads 0..31 busy-poll)
__device__ __forceinline__ void wait_rt(const unsigned* sem, int rt, unsigned target) {
    if ((int)threadIdx.x < 32) {
        const unsigned* slot = sem + (size_t)(threadIdx.x * 4 + rt) * 16;
        while (ld_flag(slot) < target) {}
    }
    __syncthreads();
}
// wait on producers ct in [lo,hi) of the same rt group (busy-poll quarters)
__device__ __forceinline__ void wait_rt_part(const unsigned* sem, int rt, unsigned target,
                                             int lo, int hi) {
    const int t = threadIdx.x;
    if (t >= lo && t < hi) {
        const unsigned* slot = sem + (size_t)(t * 4 + rt) * 16;
        while (ld_flag(slot) < target) {}
    }
    __syncthreads();
}
// wait on the 16 xh-converter slots whose j&3 == rt
__device__ __forceinline__ void wait_xh(const unsigned* sem, int rt, unsigned target) {
    if ((int)threadIdx.x < 16) {
        const unsigned* slot = sem + (size_t)(threadIdx.x * 4 + rt) * 16;
        while (ld_flag(slot) < target) {}
    }
    __syncthreads();
}

// ---------------------------------------------------------------------------
// pre-pass kernels (every call — no caching allowed)
// ---------------------------------------------------------------------------

__global__ void cvt_f32_f16(const float* __restrict__ src, half_t* __restrict__ dst, int n) {
    for (int i = blockIdx.x * blockDim.x + threadIdx.x; i < n; i += gridDim.x * blockDim.x)
        dst[i] = (half_t)src[i];
}

__global__ void fold_w1(const float* __restrict__ w1, const float* __restrict__ w2,
                        const float* __restrict__ b1, const float* __restrict__ b2,
                        half_t* __restrict__ W1f, float* __restrict__ b1f) {
    __shared__ float wy[128], b2s[128];
    const int h = blockIdx.x, tid = threadIdx.x;
    if (tid < 128) { wy[tid] = w1[(size_t)h * DIN + DX + tid]; b2s[tid] = b2[tid]; }
    __syncthreads();
    for (int k = tid; k < DX; k += 256) W1f[(size_t)h * KZ + k] = (half_t)w1[(size_t)h * DIN + k];
    for (int d = tid; d < DH; d += 256) {
        float s = 0.f;
        for (int j = 0; j < 128; ++j) s += wy[j] * w2[(size_t)j * DH + d];
        W1f[(size_t)h * KZ + DX + d] = (half_t)s;
    }
    if (tid == 0) {
        float s = 0.f;
        for (int j = 0; j < 128; ++j) s += wy[j] * b2s[j];
        b1f[h] = b1[h] + s;
    }
}

// Pack one 2048x512 gate matrix frag-major with gate interleave.
__global__ void pack512(const float* __restrict__ w, half_t* __restrict__ Wp) {
    const int u = blockIdx.x * blockDim.x + threadIdx.x;   // 0..131071
    const int lane = u & 63;
    const int n = (u >> 12) * 64 + ((u >> 6) & 3) * 16 + (lane & 15);
    const int d = ((n >> 6) << 4) | (n & 15);
    const int g = (n >> 4) & 3;
    const int k0 = ((u >> 8) & 15) * 32 + (lane >> 4) * 8;
    const float* src = w + (size_t)(g * DH + d) * DH + k0;
    half8 v;
    #pragma unroll
    for (int j = 0; j < 8; ++j) v[j] = (half_t)src[j];
    *(half8*)&Wp[(size_t)u * 8] = v;
}

__global__ void pack_bias(const float* __restrict__ bih, const float* __restrict__ bhh,
                          float* __restrict__ bP) {
    const int n = blockIdx.x * blockDim.x + threadIdx.x;   // 0..2047
    const int d = ((n >> 6) << 4) | (n & 15);
    const int g = (n >> 4) & 3;
    bP[n] = bih[g * DH + d] + bhh[g * DH + d];
}

__global__ void init_all(unsigned* sems, int n) {
    for (int k = blockIdx.x * blockDim.x + threadIdx.x; k < n; k += gridDim.x * blockDim.x)
        sems[k] = 0u;
}

// ---------------------------------------------------------------------------
// persistent kernel. Blocked activation layout for z/h0/h1:
//   addr(rt, ct, r, c) = ((rt*32 + ct)*64 + r)*16 + c   [halfs]
// Consumer k-fragment: k = j*32 + l4*8 -> block ct = 2j + (l4>>1).
// 4-way split-wait: quarter q covers j in [4q,4q+4), producers ct in [8q,8q+8).
// ---------------------------------------------------------------------------

// gemm with 4-way split-wait + counted-vmcnt pipeline.
__device__ __forceinline__ void gemm512B_sw(const half_t* __restrict__ AbaseRt,
                                            const half_t* __restrict__ BstSeg,
                                            floatx4 acc[4], int wid, int lane,
                                            const unsigned* sem, int rt, unsigned target) {
    const int l15 = lane & 15, l4 = lane >> 4;
    const half_t* a0 = AbaseRt + (l4 >> 1) * 1024 + (wid * 16 + l15) * 16 + (l4 & 1) * 8;
    half8 a[16];
    wait_rt_part(sem, rt, target, 0, 8);
    #pragma unroll
    for (int j = 0; j < 4; ++j) ldA1(a0 + j * 2048, a[j]);
    wait_rt_part(sem, rt, target, 8, 16);
    #pragma unroll
    for (int j = 4; j < 8; ++j) ldA1(a0 + j * 2048, a[j]);
    WAITVM(4);
    #pragma unroll
    for (int j = 0; j < 4; ++j)
        #pragma unroll
        for (int cf = 0; cf < 4; ++cf)
            acc[cf] = __builtin_amdgcn_mfma_f32_16x16x32_f16(
                a[j], *(const half8*)&BstSeg[(size_t)((j * 4 + cf) * 64 + lane) * 8],
                acc[cf], 0, 0, 0);
    wait_rt_part(sem, rt, target, 16, 24);
    #pragma unroll
    for (int j = 8; j < 12; ++j) ldA1(a0 + j * 2048, a[j]);
    WAITVM(4);
    #pragma unroll
    for (int j = 4; j < 8; ++j)
        #pragma unroll
        for (int cf = 0; cf < 4; ++cf)
            acc[cf] = __builtin_amdgcn_mfma_f32_16x16x32_f16(
                a[j], *(const half8*)&BstSeg[(size_t)((j * 4 + cf) * 64 + lane) * 8],
                acc[cf], 0, 0, 0);
    wait_rt_part(sem, rt, target, 24, 32);
    #pragma unroll
    for (int j = 12; j < 16; ++j) ldA1(a0 + j * 2048, a[j]);
    WAITVM(4);
    #pragma unroll
    for (int j = 8; j < 12; ++j)
        #pragma unroll
        for (int cf = 0; cf < 4; ++cf)
            acc[cf] = __builtin_amdgcn_mfma_f32_16x16x32_f16(
                a[j], *(const half8*)&BstSeg[(size_t)((j * 4 + cf) * 64 + lane) * 8],
                acc[cf], 0, 0, 0);
    WAITVM(0);
    #pragma unroll
    for (int j = 12; j < 16; ++j)
        #pragma unroll
        for (int cf = 0; cf < 4; ++cf)
            acc[cf] = __builtin_amdgcn_mfma_f32_16x16x32_f16(
                a[j], *(const half8*)&BstSeg[(size_t)((j * 4 + cf) * 64 + lane) * 8],
                acc[cf], 0, 0, 0);
}

// plain gemm (no wait — data already gated), R11 form
__device__ __forceinline__ void gemm512B(const half_t* __restrict__ AbaseRt,
                                         const half_t* __restrict__ BstSeg,
                                         floatx4 acc[4], int wid, int lane) {
    const int l15 = lane & 15, l4 = lane >> 4;
    const half_t* a0 = AbaseRt + (l4 >> 1) * 1024 + (wid * 16 + l15) * 16 + (l4 & 1) * 8;
    half8 p[8], q[8];
    #pragma unroll
    for (int j = 0; j < 8; ++j) ldA1(a0 + j * 2048, p[j]);
    #pragma unroll
    for (int j = 8; j < 16; ++j) ldA1(a0 + j * 2048, q[j - 8]);
    WAITVM(8);
    #pragma unroll
    for (int j = 0; j < 8; ++j)
        #pragma unroll
        for (int cf = 0; cf < 4; ++cf)
            acc[cf] = __builtin_amdgcn_mfma_f32_16x16x32_f16(
                p[j], *(const half8*)&BstSeg[(size_t)((j * 4 + cf) * 64 + lane) * 8],
                acc[cf], 0, 0, 0);
    WAITVM(0);
    #pragma unroll
    for (int j = 0; j < 8; ++j)
        #pragma unroll
        for (int cf = 0; cf < 4; ++cf)
            acc[cf] = __builtin_amdgcn_mfma_f32_16x16x32_f16(
                q[j], *(const half8*)&BstSeg[(size_t)(((j + 8) * 4 + cf) * 64 + lane) * 8],
                acc[cf], 0, 0, 0);
}

__global__ void __launch_bounds__(256, 1) rnn_persistent(
        const float* __restrict__ x, const half_t* __restrict__ W1h,
        const half_t* __restrict__ W1f, const float* __restrict__ b1,
        const float* __restrict__ b1f, const half_t* __restrict__ Wl0p,
        const float* __restrict__ bP0, const half_t* __restrict__ Wl1p,
        const float* __restrict__ bP1, const half_t* __restrict__ W2h,
        const float* __restrict__ b2, half_t* __restrict__ zbuf,
        half_t* __restrict__ h0buf, half_t* __restrict__ h1buf,
        half_t* __restrict__ xhst, float* __restrict__ out,
        unsigned* __restrict__ semz, unsigned* __restrict__ semh0,
        unsigned* __restrict__ semh1, unsigned* __restrict__ semxh)
{
    extern __shared__ __align__(16) char smem[];
    half_t* Bst = (half_t*)smem;                       // [0,64KB) ih, [64KB,128KB) hh
    __shared__ __align__(16) half_t bounce[64 * 20];
    const int tid = threadIdx.x;
    const int wg = blockIdx.x;
    const int lane = tid & 63, wid = tid >> 6;
    const int l15 = lane & 15, l4 = lane >> 4;
    const int grp = wg >> 7, lwg = wg & 127;
    const int ct = lwg >> 2, rt = lwg & 3;
    const floatx4 z4 = {0.f, 0.f, 0.f, 0.f};

    // stationary weight slices: 64 packed cols x 512 K x {ih, hh}
    {
        const half_t* wsrc = grp ? Wl1p : Wl0p;
        for (int i = tid; i < 8192; i += 256) {
            size_t srcoff = (i < 4096)
                ? ((size_t)ct * 32768 + (size_t)i * 8)
                : (1048576 + (size_t)ct * 32768 + (size_t)(i - 4096) * 8);
            *(half8*)&Bst[(size_t)i * 8] = *(const half8*)&wsrc[srcoff];
        }
    }
    __syncthreads();

    // blocked-layout producer store: one contiguous 2KB block per WG
    auto bounce_out = [&](const float hv[4], half_t* dstblk) {
        #pragma unroll
        for (int r = 0; r < 4; ++r)
            bounce[(wid * 16 + l4 * 4 + r) * 20 + l15] = (half_t)hv[r];
        __syncthreads();
        const int row = tid >> 2, cq = tid & 3;
        unsigned long long v = *(const unsigned long long*)&bounce[row * 20 + cq * 4];
        st_coh_u64(dstblk + row * 16 + cq * 4, v);
    };

    const float* bP = grp ? bP1 : bP0;
    const float gbi = bP[ct * 64 + l15], gbf = bP[ct * 64 + 16 + l15];
    const float gbg = bP[ct * 64 + 32 + l15], gbo = bP[ct * 64 + 48 + l15];
    float creg[4] = {0.f, 0.f, 0.f, 0.f};

    if (grp == 0) {
        const int cvR0 = rt * 64 + ((lwg - 64) >> 2) * 4;      // converter rows (own rt)
        const int isY = (lwg >= 8 && lwg < 40);
        const int yi = (lwg - 8) >> 2;                         // 0..7 (y WGs only)
        const int ylrow0 = (yi & 3) * 16;                      // local rows in own rt blk
        const int ycol = (yi >> 2) * 64 + wid * 16 + l15;      // this lane's y col
        const float ybv = isY ? b2[ycol] : 0.f;

        // deferred-y: y(tt) tile 16 rows x 64 cols from h1(tt); gated by caller
        auto do_y = [&](int tt) {
            const half_t* h1v = h1buf + (size_t)(tt & 1) * (NB * DH);
            const half_t* a0 = h1v + rt * RTBLK + (l4 >> 1) * 1024
                               + (ylrow0 + l15) * 16 + (l4 & 1) * 8;
            half8 a[16];
            #pragma unroll
            for (int j = 0; j < 16; ++j) ldA1(a0 + j * 2048, a[j]);
            floatx4 acc = z4;
            WAITVM(0);
            #pragma unroll
            for (int j = 0; j < 16; ++j)
                acc = __builtin_amdgcn_mfma_f32_16x16x32_f16(
                    a[j], *(const half8*)&W2h[(size_t)ycol * DH + j * 32 + l4 * 8],
                    acc, 0, 0, 0);
            float* yo = out + (size_t)tt * NB * DOUT;
            #pragma unroll
            for (int r = 0; r < 4; ++r)
                yo[(size_t)(rt * 64 + ylrow0 + l4 * 4 + r) * DOUT + ycol] = acc[r] + ybv;
        };

        if (lwg >= 64) {   // prologue: convert x(1) -> xh slot 1 (row-major)
            const float* xs = x + (size_t)1 * NB * DIN + (size_t)(cvR0 + (tid >> 6)) * DIN + (tid & 63) * 8;
            half_t* xd = xhst + (size_t)1 * NB * DIN + (size_t)(cvR0 + (tid >> 6)) * DIN + (tid & 63) * 8;
            st_coh_h8(xd, cvt8(xs));
            signal_slot(semxh, lwg - 64, 1u);
        }

        floatx4 accC[4] = {z4, z4, z4, z4};            // carried L0hh partial
        for (int t = 0; t < NT; ++t) {
            const int p = t & 1;
            half_t* z_t  = zbuf  + (size_t)p * (NB * DH);
            half_t* h0_t = h0buf + (size_t)p * (NB * DH);

            gemm512B_sw(z_t + rt * RTBLK, Bst, accC, wid, lane, semz, rt, (unsigned)(t + 1));
            float hv[4];
            #pragma unroll
            for (int r = 0; r < 4; ++r) {
                const float gi = accC[0][r] + gbi, gf = accC[1][r] + gbf;
                const float gg = accC[2][r] + gbg, go = accC[3][r] + gbo;
                const float cn = sigm(gf) * creg[r] + sigm(gi) * tanhx(gg);
                creg[r] = cn;
                hv[r] = sigm(go) * tanhx(cn);
            }
            bounce_out(hv, h0_t + (rt * 32 + ct) * 1024);
            signal_slot(semh0, lwg, (unsigned)(t + 1));

            #pragma unroll
            for (int cf = 0; cf < 4; ++cf) accC[cf] = z4;
            if (t + 1 < NT)
                gemm512B_sw(h0_t + rt * RTBLK, Bst + 32768, accC, wid, lane,
                            semh0, rt, (unsigned)(t + 1));   // h0(t) @ W0hh

            if (isY) {
                if (t > 0) {             // deferred y(t-1): semh1 >= t implied by z(t) wait
                    wait_rt(semh1, rt, (unsigned)t);
                    do_y(t - 1);
                }
            } else if (lwg >= 64 && t + 2 < NT) {
                // convert x(t+2) -> xh slot (t+2)&1 (overwrite gated by semz wait above)
                const float* xs = x + (size_t)(t + 2) * NB * DIN + (size_t)(cvR0 + (tid >> 6)) * DIN + (tid & 63) * 8;
                half_t* xd = xhst + (size_t)((t + 2) & 1) * (NB * DIN) + (size_t)(cvR0 + (tid >> 6)) * DIN + (tid & 63) * 8;
                st_coh_h8(xd, cvt8(xs));
                signal_slot(semxh, lwg - 64, (unsigned)(t + 2));
            }
        }
        if (isY) {                       // epilogue: y(NT-1)
            wait_rt(semh1, rt, (unsigned)NT);
            do_y(NT - 1);
        }
    } else {
        const int zc = lwg >> 2, zr = lwg & 3;         // zr == rt
        const int zlrow = wid * 16 + l15;              // local row in rt block
        const int zarow = zr * 64 + zlrow;             // global row (for xh)
        const int zn = zc * 16 + l15;
        const float zb1f = b1f[zn];

        // prologue: z(0) = relu(x[0] @ W1^T + b1) (f32 A, full K=512)
        {
            floatx4 acc = z4;
            #pragma unroll 4
            for (int kf = 0; kf < 16; ++kf) {
                half8 a = cvt8(x + (size_t)zarow * DIN + kf * 32 + l4 * 8);
                half8 b = *(const half8*)&W1h[(size_t)zn * DIN + kf * 32 + l4 * 8];
                acc = __builtin_amdgcn_mfma_f32_16x16x32_f16(a, b, acc, 0, 0, 0);
            }
            const float bb = b1[zn];
            float zv[4];
            #pragma unroll
            for (int r = 0; r < 4; ++r) zv[r] = fmaxf(acc[r] + bb, 0.f);
            bounce_out(zv, zbuf + (zr * 32 + zc) * 1024);
            signal_slot(semz, lwg, 1u);
        }

        floatx4 acc1[4];
        for (int t = 0; t < NT; ++t) {
            const int p = t & 1;
            half_t* z_n  = zbuf  + (size_t)(p ^ 1) * (NB * DH);
            half_t* h0_t = h0buf + (size_t)p * (NB * DH);
            half_t* h1_t = h1buf + (size_t)p * (NB * DH);
            half_t* h1_p = h1buf + (size_t)(p ^ 1) * (NB * DH);

            // off-path: L1hh partial from h1(t-1) (reads gated by prev-iter semh1 wait)
            #pragma unroll
            for (int cf = 0; cf < 4; ++cf) acc1[cf] = z4;
            if (t > 0)
                gemm512B(h1_p + rt * RTBLK, Bst + 32768, acc1, wid, lane);

            // off-path: z(t+1) x-part from fp16 xh (row-major)
            floatx4 accZ = z4;
            if (t + 1 < NT) {
                wait_xh(semxh, rt, (unsigned)(t + 1));
                const half_t* xh_n = xhst + (size_t)((t + 1) & 1) * (NB * DIN);
                const half_t* xb = xh_n + (size_t)zarow * DIN + l4 * 8;
                const half_t* wb = W1f + (size_t)zn * KZ + l4 * 8;
                half8 xf[12], bx[12];
                ldA8(xb, xf[0], xf[1], xf[2], xf[3], xf[4], xf[5], xf[6], xf[7]);
                ldA4(xb + 256, xf[8], xf[9], xf[10], xf[11]);
                ldC8(wb, bx[0], bx[1], bx[2], bx[3], bx[4], bx[5], bx[6], bx[7]);
                ldC4(wb + 256, bx[8], bx[9], bx[10], bx[11]);
                WAITVM(0);
                #pragma unroll
                for (int j = 0; j < 12; ++j)
                    accZ = __builtin_amdgcn_mfma_f32_16x16x32_f16(xf[j], bx[j], accZ, 0, 0, 0);
            }

            gemm512B_sw(h0_t + rt * RTBLK, Bst, acc1, wid, lane,
                        semh0, rt, (unsigned)(t + 1));        // + h0(t) @ W1ih
            float hv[4];
            #pragma unroll
            for (int r = 0; r < 4; ++r) {
                const float gi = acc1[0][r] + gbi, gf = acc1[1][r] + gbf;
                const float gg = acc1[2][r] + gbg, go = acc1[3][r] + gbo;
                const float cn = sigm(gf) * creg[r] + sigm(gi) * tanhx(gg);
                creg[r] = cn;
                hv[r] = sigm(go) * tanhx(cn);
            }
            bounce_out(hv, h1_t + (rt * 32 + ct) * 1024);
            signal_slot(semh1, lwg, (unsigned)(t + 1));

            // preload z h-part weights while h1 stragglers finish
            half8 bh[16];
            #pragma unroll
            for (int j = 0; j < 16; ++j)
                bh[j] = *(const half8*)&W1f[(size_t)zn * KZ + DX + j * 32 + l4 * 8];

            if (t + 1 < NT) {   // z(t+1) h-part with 4-way split-wait on h1 producers
                const half_t* a0 = h1_t + rt * RTBLK + (l4 >> 1) * 1024 + zlrow * 16 + (l4 & 1) * 8;
                half8 hf[16];
                wait_rt_part(semh1, rt, (unsigned)(t + 1), 0, 8);
                #pragma unroll
                for (int j = 0; j < 4; ++j) ldA1(a0 + j * 2048, hf[j]);
                wait_rt_part(semh1, rt, (unsigned)(t + 1), 8, 16);
                #pragma unroll
                for (int j = 4; j < 8; ++j) ldA1(a0 + j * 2048, hf[j]);
                WAITVM(4);
                #pragma unroll
                for (int j = 0; j < 4; ++j)
                    accZ = __builtin_amdgcn_mfma_f32_16x16x32_f16(hf[j], bh[j], accZ, 0, 0, 0);
                wait_rt_part(semh1, rt, (unsigned)(t + 1), 16, 24);
                #pragma unroll
                for (int j = 8; j < 12; ++j) ldA1(a0 + j * 2048, hf[j]);
                WAITVM(4);
                #pragma unroll
                for (int j = 4; j < 8; ++j)
                    accZ = __builtin_amdgcn_mfma_f32_16x16x32_f16(hf[j], bh[j], accZ, 0, 0, 0);
                wait_rt_part(semh1, rt, (unsigned)(t + 1), 24, 32);
                #pragma unroll
                for (int j = 12; j < 16; ++j) ldA1(a0 + j * 2048, hf[j]);
                WAITVM(4);
                #pragma unroll
                for (int j = 8; j < 12; ++j)
                    accZ = __builtin_amdgcn_mfma_f32_16x16x32_f16(hf[j], bh[j], accZ, 0, 0, 0);
                WAITVM(0);
                #pragma unroll
                for (int j = 12; j < 16; ++j)
                    accZ = __builtin_amdgcn_mfma_f32_16x16x32_f16(hf[j], bh[j], accZ, 0, 0, 0);
                float zv[4];
                #pragma unroll
                for (int r = 0; r < 4; ++r) zv[r] = fmaxf(accZ[r] + zb1f, 0.f);
                bounce_out(zv, z_n + (zr * 32 + zc) * 1024);
                signal_slot(semz, lwg, (unsigned)(t + 2));
            }
        }
    }
}

// ---------------------------------------------------------------------------

extern "C" void kernel_launch(void* const* d_in, const int* in_sizes, int n_in,
                              void* d_out, int out_size, void* d_ws, size_t ws_size,
                              hipStream_t stream) {
    const float* x    = (const float*)d_in[0];
    const float* w1   = (const float*)d_in[1];
    const float* b1   = (const float*)d_in[2];
    const float* w_ih = (const float*)d_in[3];
    const float* w_hh = (const float*)d_in[4];
    const float* b_ih = (const float*)d_in[5];
    const float* b_hh = (const float*)d_in[6];
    const float* w2   = (const float*)d_in[7];
    const float* b2   = (const float*)d_in[8];
    float* out = (float*)d_out;
    (void)in_sizes; (void)n_in; (void)out_size; (void)ws_size;

    char* ws = (char*)d_ws;
    size_t off = 0;
    auto take = [&](size_t bytes) -> char* {
        char* p = ws + off;
        off += (bytes + 255) & ~(size_t)255;
        return p;
    };
    half_t* W1h  = (half_t*)take((size_t)512 * 512 * 2);
    half_t* W2h  = (half_t*)take((size_t)128 * 512 * 2);
    half_t* W1f  = (half_t*)take((size_t)512 * KZ * 2);
    half_t* Wl0p = (half_t*)take((size_t)NG * 1024 * 2);   // [ih 2MB | hh 2MB]
    half_t* Wl1p = (half_t*)take((size_t)NG * 1024 * 2);
    float*  b1f  = (float*)take((size_t)512 * 4);
    float*  bP0  = (float*)take((size_t)NG * 4);
    float*  bP1  = (float*)take((size_t)NG * 4);
    half_t* zbuf  = (half_t*)take((size_t)2 * NB * DH * 2);
    half_t* h0buf = (half_t*)take((size_t)2 * NB * DH * 2);
    half_t* h1buf = (half_t*)take((size_t)2 * NB * DH * 2);
    half_t* xhst  = (half_t*)take((size_t)2 * NB * DIN * 2);
    unsigned* semz  = (unsigned*)take((size_t)128 * 16 * 4);
    unsigned* semh0 = (unsigned*)take((size_t)128 * 16 * 4);
    unsigned* semh1 = (unsigned*)take((size_t)128 * 16 * 4);
    unsigned* semxh = (unsigned*)take((size_t)64 * 16 * 4);

    cvt_f32_f16<<<256, 256, 0, stream>>>(w1, W1h, 512 * 512);
    cvt_f32_f16<<<64, 256, 0, stream>>>(w2, W2h, 128 * 512);
    fold_w1<<<512, 256, 0, stream>>>(w1, w2, b1, b2, W1f, b1f);
    pack512<<<512, 256, 0, stream>>>(w_ih, Wl0p);
    pack512<<<512, 256, 0, stream>>>(w_hh, Wl0p + 1048576);
    pack512<<<512, 256, 0, stream>>>(w_ih + (size_t)NG * DH, Wl1p);
    pack512<<<512, 256, 0, stream>>>(w_hh + (size_t)NG * DH, Wl1p + 1048576);
    pack_bias<<<8, 256, 0, stream>>>(b_ih, b_hh, bP0);
    pack_bias<<<8, 256, 0, stream>>>(b_ih + NG, b_hh + NG, bP1);
    init_all<<<8, 256, 0, stream>>>(semz, (3 * 128 + 64) * 16);

    hipFuncSetAttribute((const void*)rnn_persistent,
                        hipFuncAttributeMaxDynamicSharedMemorySize, SMEM);

    void* args[] = { (void*)&x, (void*)&W1h, (void*)&W1f, (void*)&b1, (void*)&b1f,
                     (void*)&Wl0p, (void*)&bP0, (void*)&Wl1p, (void*)&bP1,
                     (void*)&W2h, (void*)&b2, (void*)&zbuf, (void*)&h0buf,
                     (void*)&h1buf, (void*)&xhst, (void*)&out,
                     (void*)&semz, (void*)&semh0, (void*)&semh1, (void*)&semxh };
    hipError_t e = hipLaunchCooperativeKernel((void*)rnn_persistent, dim3(NWG), dim3(256),
                                              args, SMEM, stream);
    if (e != hipSuccess) {
        rnn_persistent<<<dim3(NWG), dim3(256), SMEM, stream>>>(
            x, W1h, W1f, b1, b1f, Wl0p, bP0, Wl1p, bP1, W2h, b2,
            zbuf, h0buf, h1buf, xhst, out, semz, semh0, semh1, semxh);
    }
}

// Round 16
// 3417.688 us; speedup vs baseline: 1.0469x; 1.0469x over previous
//
#include <hip/hip_runtime.h>

typedef _Float16 half_t;
typedef _Float16 half8 __attribute__((ext_vector_type(8)));
typedef float floatx4 __attribute__((ext_vector_type(4)));

#define NT   300
#define NB   256
#define DIN  512
#define DH   512
#define DOUT 128
#define DX   384        // IN - OUT
#define KZ   896        // folded z GEMM K: 384 (x) + 512 (h1)
#define NG   2048       // 4*DH gate rows
#define NWG  256
#define SMEM 131072     // 64KB ih-slice + 64KB hh-slice per WG
#define RTBLK 32768     // halfs per rt block in blocked activation layout (32*64*16)

#define WAITVM(N) do { asm volatile("s_waitcnt vmcnt(" #N ")" ::: "memory"); \
                       __builtin_amdgcn_sched_barrier(0); } while (0)

// ---------------------------------------------------------------------------
// helpers
// ---------------------------------------------------------------------------

__device__ __forceinline__ float sigm(float x)  { return __builtin_amdgcn_rcpf(1.f + __expf(-x)); }
__device__ __forceinline__ float tanhx(float x) { return 1.f - 2.f * __builtin_amdgcn_rcpf(__expf(2.f * x) + 1.f); }

__device__ __forceinline__ half8 cvt8(const float* s) {
    float4 f0 = *(const float4*)s, f1 = *(const float4*)(s + 4);
    half8 h;
    h[0] = (half_t)f0.x; h[1] = (half_t)f0.y; h[2] = (half_t)f0.z; h[3] = (half_t)f0.w;
    h[4] = (half_t)f1.x; h[5] = (half_t)f1.y; h[6] = (half_t)f1.z; h[7] = (half_t)f1.w;
    return h;
}

// single coherent (LLC) 16B load — caller batches and counts via WAITVM
__device__ __forceinline__ void ldA1(const half_t* a, half8& r) {
    asm volatile("global_load_dwordx4 %0, %1, off sc0 sc1" : "=&v"(r) : "v"(a) : "memory");
}

// coherent batched loads over row-major data (xh), single base + imm offsets
__device__ __forceinline__ void ldA8(const half_t* b, half8& r0, half8& r1, half8& r2, half8& r3,
                                     half8& r4, half8& r5, half8& r6, half8& r7) {
    asm volatile(
        "global_load_dwordx4 %0, %8, off sc0 sc1\n\t"
        "global_load_dwordx4 %1, %8, off offset:64 sc0 sc1\n\t"
        "global_load_dwordx4 %2, %8, off offset:128 sc0 sc1\n\t"
        "global_load_dwordx4 %3, %8, off offset:192 sc0 sc1\n\t"
        "global_load_dwordx4 %4, %8, off offset:256 sc0 sc1\n\t"
        "global_load_dwordx4 %5, %8, off offset:320 sc0 sc1\n\t"
        "global_load_dwordx4 %6, %8, off offset:384 sc0 sc1\n\t"
        "global_load_dwordx4 %7, %8, off offset:448 sc0 sc1"
        : "=&v"(r0), "=&v"(r1), "=&v"(r2), "=&v"(r3),
          "=&v"(r4), "=&v"(r5), "=&v"(r6), "=&v"(r7)
        : "v"(b) : "memory");
}
__device__ __forceinline__ void ldA4(const half_t* b, half8& r0, half8& r1, half8& r2, half8& r3) {
    asm volatile(
        "global_load_dwordx4 %0, %4, off sc0 sc1\n\t"
        "global_load_dwordx4 %1, %4, off offset:64 sc0 sc1\n\t"
        "global_load_dwordx4 %2, %4, off offset:128 sc0 sc1\n\t"
        "global_load_dwordx4 %3, %4, off offset:192 sc0 sc1"
        : "=&v"(r0), "=&v"(r1), "=&v"(r2), "=&v"(r3)
        : "v"(b) : "memory");
}
// cached (L1/L2) batched loads for read-only prepass outputs (W1f)
__device__ __forceinline__ void ldC8(const half_t* b, half8& r0, half8& r1, half8& r2, half8& r3,
                                     half8& r4, half8& r5, half8& r6, half8& r7) {
    asm volatile(
        "global_load_dwordx4 %0, %8, off\n\t"
        "global_load_dwordx4 %1, %8, off offset:64\n\t"
        "global_load_dwordx4 %2, %8, off offset:128\n\t"
        "global_load_dwordx4 %3, %8, off offset:192\n\t"
        "global_load_dwordx4 %4, %8, off offset:256\n\t"
        "global_load_dwordx4 %5, %8, off offset:320\n\t"
        "global_load_dwordx4 %6, %8, off offset:384\n\t"
        "global_load_dwordx4 %7, %8, off offset:448"
        : "=&v"(r0), "=&v"(r1), "=&v"(r2), "=&v"(r3),
          "=&v"(r4), "=&v"(r5), "=&v"(r6), "=&v"(r7)
        : "v"(b) : "memory");
}
__device__ __forceinline__ void ldC4(const half_t* b, half8& r0, half8& r1, half8& r2, half8& r3) {
    asm volatile(
        "global_load_dwordx4 %0, %4, off\n\t"
        "global_load_dwordx4 %1, %4, off offset:64\n\t"
        "global_load_dwordx4 %2, %4, off offset:128\n\t"
        "global_load_dwordx4 %3, %4, off offset:192"
        : "=&v"(r0), "=&v"(r1), "=&v"(r2), "=&v"(r3)
        : "v"(b) : "memory");
}

__device__ __forceinline__ void st_coh_u64(half_t* p, unsigned long long v) {
    asm volatile("global_store_dwordx2 %0, %1, off sc0 sc1" :: "v"(p), "v"(v) : "memory");
}
__device__ __forceinline__ void st_coh_h8(half_t* p, half8 v) {
    asm volatile("global_store_dwordx4 %0, %1, off sc0 sc1" :: "v"(p), "v"(v) : "memory");
}
__device__ __forceinline__ unsigned ld_flag(const unsigned* p) {
    unsigned v;
    asm volatile("global_load_dword %0, %1, off sc0 sc1\n\ts_waitcnt vmcnt(0)"
                 : "=v"(v) : "v"(p) : "memory");
    return v;
}
__device__ __forceinline__ void st_flag(unsigned* p, unsigned v) {
    asm volatile("global_store_dword %0, %1, off sc0 sc1" :: "v"(p), "v"(v) : "memory");
}

// producer WG signals its own slot (after draining its data stores to LLC)
__device__ __forceinline__ void signal_slot(unsigned* sem, int slot, unsigned value) {
    asm volatile("s_waitcnt vmcnt(0) lgkmcnt(0)" ::: "memory");
    __syncthreads();
    if (threadIdx.x == 0) st_flag(sem + (size_t)slot * 16, value);
}
// wait on all 32 producers whose lwg&3 == rt (threads 0..31 poll in parallel)
__device__ __forceinline__ void wait_rt(const unsigned* sem, int rt, unsigned target) {
    if ((int)threadIdx.x < 32) {
        const unsigned* slot = sem + (size_t)(threadIdx.x * 4 + rt) * 16;
        while (ld_flag(slot) < target) __builtin_amdgcn_s_sleep(1);
    }
    __syncthreads();
}
// wait on producers ct in [lo,hi) of the same rt group (split-wait halves)
__device__ __forceinline__ void wait_rt_part(const unsigned* sem, int rt, unsigned target,
                                             int lo, int hi) {
    const int t = threadIdx.x;
    if (t >= lo && t < hi) {
        const unsigned* slot = sem + (size_t)(t * 4 + rt) * 16;
        while (ld_flag(slot) < target) __builtin_amdgcn_s_sleep(1);
    }
    __syncthreads();
}
// wait on the 16 xh-converter slots whose j&3 == rt
__device__ __forceinline__ void wait_xh(const unsigned* sem, int rt, unsigned target) {
    if ((int)threadIdx.x < 16) {
        const unsigned* slot = sem + (size_t)(threadIdx.x * 4 + rt) * 16;
        while (ld_flag(slot) < target) __builtin_amdgcn_s_sleep(1);
    }
    __syncthreads();
}

// ---------------------------------------------------------------------------
// pre-pass kernels (every call — no caching allowed)
// ---------------------------------------------------------------------------

__global__ void cvt_f32_f16(const float* __restrict__ src, half_t* __restrict__ dst, int n) {
    for (int i = blockIdx.x * blockDim.x + threadIdx.x; i < n; i += gridDim.x * blockDim.x)
        dst[i] = (half_t)src[i];
}

__global__ void fold_w1(const float* __restrict__ w1, const float* __restrict__ w2,
                        const float* __restrict__ b1, const float* __restrict__ b2,
                        half_t* __restrict__ W1f, float* __restrict__ b1f) {
    __shared__ float wy[128], b2s[128];
    const int h = blockIdx.x, tid = threadIdx.x;
    if (tid < 128) { wy[tid] = w1[(size_t)h * DIN + DX + tid]; b2s[tid] = b2[tid]; }
    __syncthreads();
    for (int k = tid; k < DX; k += 256) W1f[(size_t)h * KZ + k] = (half_t)w1[(size_t)h * DIN + k];
    for (int d = tid; d < DH; d += 256) {
        float s = 0.f;
        for (int j = 0; j < 128; ++j) s += wy[j] * w2[(size_t)j * DH + d];
        W1f[(size_t)h * KZ + DX + d] = (half_t)s;
    }
    if (tid == 0) {
        float s = 0.f;
        for (int j = 0; j < 128; ++j) s += wy[j] * b2s[j];
        b1f[h] = b1[h] + s;
    }
}

// Pack one 2048x512 gate matrix frag-major with gate interleave.
__global__ void pack512(const float* __restrict__ w, half_t* __restrict__ Wp) {
    const int u = blockIdx.x * blockDim.x + threadIdx.x;   // 0..131071
    const int lane = u & 63;
    const int n = (u >> 12) * 64 + ((u >> 6) & 3) * 16 + (lane & 15);
    const int d = ((n >> 6) << 4) | (n & 15);
    const int g = (n >> 4) & 3;
    const int k0 = ((u >> 8) & 15) * 32 + (lane >> 4) * 8;
    const float* src = w + (size_t)(g * DH + d) * DH + k0;
    half8 v;
    #pragma unroll
    for (int j = 0; j < 8; ++j) v[j] = (half_t)src[j];
    *(half8*)&Wp[(size_t)u * 8] = v;
}

__global__ void pack_bias(const float* __restrict__ bih, const float* __restrict__ bhh,
                          float* __restrict__ bP) {
    const int n = blockIdx.x * blockDim.x + threadIdx.x;   // 0..2047
    const int d = ((n >> 6) << 4) | (n & 15);
    const int g = (n >> 4) & 3;
    bP[n] = bih[g * DH + d] + bhh[g * DH + d];
}

__global__ void init_all(unsigned* sems, int n) {
    for (int k = blockIdx.x * blockDim.x + threadIdx.x; k < n; k += gridDim.x * blockDim.x)
        sems[k] = 0u;
}

// ---------------------------------------------------------------------------
// persistent kernel. Blocked activation layout for z/h0/h1:
//   addr(rt, ct, r, c) = ((rt*32 + ct)*64 + r)*16 + c   [halfs]
// Producer WG (rt,ct) writes one contiguous 2KB block (fast vmcnt drain).
// Consumer k-fragment: k = j*32 + l4*8 -> block ct = 2j + (l4>>1),
//   koff = (l4&1)*8; lane base a0 + j*2048 halfs.
// Split-wait: K-half j=0..7 depends on producers ct=0..15, j=8..15 on ct=16..31.
// y spread over 32 WGs (8 per rt): 16-row x 64-col tiles -> uniform grp0 cohort.
// ---------------------------------------------------------------------------

// gemm with integrated split-wait: wait ct[0,16) -> issue lo loads ->
// wait ct[16,32) -> issue hi loads -> mfma lo -> mfma hi.
__device__ __forceinline__ void gemm512B_sw(const half_t* __restrict__ AbaseRt,
                                            const half_t* __restrict__ BstSeg,
                                            floatx4 acc[4], int wid, int lane,
                                            const unsigned* sem, int rt, unsigned target) {
    const int l15 = lane & 15, l4 = lane >> 4;
    const half_t* a0 = AbaseRt + (l4 >> 1) * 1024 + (wid * 16 + l15) * 16 + (l4 & 1) * 8;
    half8 p[8], q[8];
    wait_rt_part(sem, rt, target, 0, 16);
    #pragma unroll
    for (int j = 0; j < 8; ++j) ldA1(a0 + j * 2048, p[j]);
    wait_rt_part(sem, rt, target, 16, 32);
    #pragma unroll
    for (int j = 8; j < 16; ++j) ldA1(a0 + j * 2048, q[j - 8]);
    WAITVM(8);
    #pragma unroll
    for (int j = 0; j < 8; ++j)
        #pragma unroll
        for (int cf = 0; cf < 4; ++cf)
            acc[cf] = __builtin_amdgcn_mfma_f32_16x16x32_f16(
                p[j], *(const half8*)&BstSeg[(size_t)((j * 4 + cf) * 64 + lane) * 8],
                acc[cf], 0, 0, 0);
    WAITVM(0);
    #pragma unroll
    for (int j = 0; j < 8; ++j)
        #pragma unroll
        for (int cf = 0; cf < 4; ++cf)
            acc[cf] = __builtin_amdgcn_mfma_f32_16x16x32_f16(
                q[j], *(const half8*)&BstSeg[(size_t)(((j + 8) * 4 + cf) * 64 + lane) * 8],
                acc[cf], 0, 0, 0);
}

// plain gemm (no wait — data already gated), R11 form
__device__ __forceinline__ void gemm512B(const half_t* __restrict__ AbaseRt,
                                         const half_t* __restrict__ BstSeg,
                                         floatx4 acc[4], int wid, int lane) {
    const int l15 = lane & 15, l4 = lane >> 4;
    const half_t* a0 = AbaseRt + (l4 >> 1) * 1024 + (wid * 16 + l15) * 16 + (l4 & 1) * 8;
    half8 p[8], q[8];
    #pragma unroll
    for (int j = 0; j < 8; ++j) ldA1(a0 + j * 2048, p[j]);
    #pragma unroll
    for (int j = 8; j < 16; ++j) ldA1(a0 + j * 2048, q[j - 8]);
    WAITVM(8);
    #pragma unroll
    for (int j = 0; j < 8; ++j)
        #pragma unroll
        for (int cf = 0; cf < 4; ++cf)
            acc[cf] = __builtin_amdgcn_mfma_f32_16x16x32_f16(
                p[j], *(const half8*)&BstSeg[(size_t)((j * 4 + cf) * 64 + lane) * 8],
                acc[cf], 0, 0, 0);
    WAITVM(0);
    #pragma unroll
    for (int j = 0; j < 8; ++j)
        #pragma unroll
        for (int cf = 0; cf < 4; ++cf)
            acc[cf] = __builtin_amdgcn_mfma_f32_16x16x32_f16(
                q[j], *(const half8*)&BstSeg[(size_t)(((j + 8) * 4 + cf) * 64 + lane) * 8],
                acc[cf], 0, 0, 0);
}

__global__ void __launch_bounds__(256, 1) rnn_persistent(
        const float* __restrict__ x, const half_t* __restrict__ W1h,
        const half_t* __restrict__ W1f, const float* __restrict__ b1,
        const float* __restrict__ b1f, const half_t* __restrict__ Wl0p,
        const float* __restrict__ bP0, const half_t* __restrict__ Wl1p,
        const float* __restrict__ bP1, const half_t* __restrict__ W2h,
        const float* __restrict__ b2, half_t* __restrict__ zbuf,
        half_t* __restrict__ h0buf, half_t* __restrict__ h1buf,
        half_t* __restrict__ xhst, float* __restrict__ out,
        unsigned* __restrict__ semz, unsigned* __restrict__ semh0,
        unsigned* __restrict__ semh1, unsigned* __restrict__ semxh)
{
    extern __shared__ __align__(16) char smem[];
    half_t* Bst = (half_t*)smem;                       // [0,64KB) ih, [64KB,128KB) hh
    __shared__ __align__(16) half_t bounce[64 * 20];
    const int tid = threadIdx.x;
    const int wg = blockIdx.x;
    const int lane = tid & 63, wid = tid >> 6;
    const int l15 = lane & 15, l4 = lane >> 4;
    const int grp = wg >> 7, lwg = wg & 127;
    const int ct = lwg >> 2, rt = lwg & 3;
    const floatx4 z4 = {0.f, 0.f, 0.f, 0.f};

    // stationary weight slices: 64 packed cols x 512 K x {ih, hh}
    {
        const half_t* wsrc = grp ? Wl1p : Wl0p;
        for (int i = tid; i < 8192; i += 256) {
            size_t srcoff = (i < 4096)
                ? ((size_t)ct * 32768 + (size_t)i * 8)
                : (1048576 + (size_t)ct * 32768 + (size_t)(i - 4096) * 8);
            *(half8*)&Bst[(size_t)i * 8] = *(const half8*)&wsrc[srcoff];
        }
    }
    __syncthreads();

    // blocked-layout producer store: one contiguous 2KB block per WG
    auto bounce_out = [&](const float hv[4], half_t* dstblk) {
        #pragma unroll
        for (int r = 0; r < 4; ++r)
            bounce[(wid * 16 + l4 * 4 + r) * 20 + l15] = (half_t)hv[r];
        __syncthreads();
        const int row = tid >> 2, cq = tid & 3;
        unsigned long long v = *(const unsigned long long*)&bounce[row * 20 + cq * 4];
        st_coh_u64(dstblk + row * 16 + cq * 4, v);
    };

    const float* bP = grp ? bP1 : bP0;
    const float gbi = bP[ct * 64 + l15], gbf = bP[ct * 64 + 16 + l15];
    const float gbg = bP[ct * 64 + 32 + l15], gbo = bP[ct * 64 + 48 + l15];
    float creg[4] = {0.f, 0.f, 0.f, 0.f};

    if (grp == 0) {
        const int cvR0 = rt * 64 + ((lwg - 64) >> 2) * 4;      // converter rows (own rt)
        const int isY = (lwg >= 8 && lwg < 40);
        const int yi = (lwg - 8) >> 2;                         // 0..7 (y WGs only)
        const int ylrow0 = (yi & 3) * 16;                      // local rows in own rt blk
        const int ycol = (yi >> 2) * 64 + wid * 16 + l15;      // this lane's y col
        const float ybv = isY ? b2[ycol] : 0.f;

        // deferred-y: y(tt) tile 16 rows x 64 cols from h1(tt); gated by caller
        auto do_y = [&](int tt) {
            const half_t* h1v = h1buf + (size_t)(tt & 1) * (NB * DH);
            const half_t* a0 = h1v + rt * RTBLK + (l4 >> 1) * 1024
                               + (ylrow0 + l15) * 16 + (l4 & 1) * 8;
            half8 a[16];
            #pragma unroll
            for (int j = 0; j < 16; ++j) ldA1(a0 + j * 2048, a[j]);
            floatx4 acc = z4;
            WAITVM(0);
            #pragma unroll
            for (int j = 0; j < 16; ++j)
                acc = __builtin_amdgcn_mfma_f32_16x16x32_f16(
                    a[j], *(const half8*)&W2h[(size_t)ycol * DH + j * 32 + l4 * 8],
                    acc, 0, 0, 0);
            float* yo = out + (size_t)tt * NB * DOUT;
            #pragma unroll
            for (int r = 0; r < 4; ++r)
                yo[(size_t)(rt * 64 + ylrow0 + l4 * 4 + r) * DOUT + ycol] = acc[r] + ybv;
        };

        if (lwg >= 64) {   // prologue: convert x(1) -> xh slot 1 (row-major)
            const float* xs = x + (size_t)1 * NB * DIN + (size_t)(cvR0 + (tid >> 6)) * DIN + (tid & 63) * 8;
            half_t* xd = xhst + (size_t)1 * NB * DIN + (size_t)(cvR0 + (tid >> 6)) * DIN + (tid & 63) * 8;
            st_coh_h8(xd, cvt8(xs));
            signal_slot(semxh, lwg - 64, 1u);
        }

        floatx4 accC[4] = {z4, z4, z4, z4};            // carried L0hh partial
        for (int t = 0; t < NT; ++t) {
            const int p = t & 1;
            half_t* z_t  = zbuf  + (size_t)p * (NB * DH);
            half_t* h0_t = h0buf + (size_t)p * (NB * DH);

            gemm512B_sw(z_t + rt * RTBLK, Bst, accC, wid, lane, semz, rt, (unsigned)(t + 1));
            float hv[4];
            #pragma unroll
            for (int r = 0; r < 4; ++r) {
                const float gi = accC[0][r] + gbi, gf = accC[1][r] + gbf;
                const float gg = accC[2][r] + gbg, go = accC[3][r] + gbo;
                const float cn = sigm(gf) * creg[r] + sigm(gi) * tanhx(gg);
                creg[r] = cn;
                hv[r] = sigm(go) * tanhx(cn);
            }
            bounce_out(hv, h0_t + (rt * 32 + ct) * 1024);
            signal_slot(semh0, lwg, (unsigned)(t + 1));

            #pragma unroll
            for (int cf = 0; cf < 4; ++cf) accC[cf] = z4;
            if (t + 1 < NT)
                gemm512B_sw(h0_t + rt * RTBLK, Bst + 32768, accC, wid, lane,
                            semh0, rt, (unsigned)(t + 1));   // h0(t) @ W0hh

            if (isY) {
                if (t > 0) {             // deferred y(t-1): semh1 >= t implied by z(t) wait
                    wait_rt(semh1, rt, (unsigned)t);
                    do_y(t - 1);
                }
            } else if (lwg >= 64 && t + 2 < NT) {
                // convert x(t+2) -> xh slot (t+2)&1 (overwrite gated by semz wait above)
                const float* xs = x + (size_t)(t + 2) * NB * DIN + (size_t)(cvR0 + (tid >> 6)) * DIN + (tid & 63) * 8;
                half_t* xd = xhst + (size_t)((t + 2) & 1) * (NB * DIN) + (size_t)(cvR0 + (tid >> 6)) * DIN + (tid & 63) * 8;
                st_coh_h8(xd, cvt8(xs));
                signal_slot(semxh, lwg - 64, (unsigned)(t + 2));
            }
        }
        if (isY) {                       // epilogue: y(NT-1)
            wait_rt(semh1, rt, (unsigned)NT);
            do_y(NT - 1);
        }
    } else {
        const int zc = lwg >> 2, zr = lwg & 3;         // zr == rt
        const int zlrow = wid * 16 + l15;              // local row in rt block
        const int zarow = zr * 64 + zlrow;             // global row (for xh)
        const int zn = zc * 16 + l15;
        const float zb1f = b1f[zn];

        // prologue: z(0) = relu(x[0] @ W1^T + b1) (f32 A, full K=512)
        {
            floatx4 acc = z4;
            #pragma unroll 4
            for (int kf = 0; kf < 16; ++kf) {
                half8 a = cvt8(x + (size_t)zarow * DIN + kf * 32 + l4 * 8);
                half8 b = *(const half8*)&W1h[(size_t)zn * DIN + kf * 32 + l4 * 8];
                acc = __builtin_amdgcn_mfma_f32_16x16x32_f16(a, b, acc, 0, 0, 0);
            }
            const float bb = b1[zn];
            float zv[4];
            #pragma unroll
            for (int r = 0; r < 4; ++r) zv[r] = fmaxf(acc[r] + bb, 0.f);
            bounce_out(zv, zbuf + (zr * 32 + zc) * 1024);
            signal_slot(semz, lwg, 1u);
        }

        floatx4 acc1[4];
        for (int t = 0; t < NT; ++t) {
            const int p = t & 1;
            half_t* z_n  = zbuf  + (size_t)(p ^ 1) * (NB * DH);
            half_t* h0_t = h0buf + (size_t)p * (NB * DH);
            half_t* h1_t = h1buf + (size_t)p * (NB * DH);
            half_t* h1_p = h1buf + (size_t)(p ^ 1) * (NB * DH);

            // off-path: L1hh partial from h1(t-1) (reads gated by prev-iter semh1 wait)
            #pragma unroll
            for (int cf = 0; cf < 4; ++cf) acc1[cf] = z4;
            if (t > 0)
                gemm512B(h1_p + rt * RTBLK, Bst + 32768, acc1, wid, lane);

            // off-path: z(t+1) x-part from fp16 xh (row-major)
            floatx4 accZ = z4;
            if (t + 1 < NT) {
                wait_xh(semxh, rt, (unsigned)(t + 1));
                const half_t* xh_n = xhst + (size_t)((t + 1) & 1) * (NB * DIN);
                const half_t* xb = xh_n + (size_t)zarow * DIN + l4 * 8;
                const half_t* wb = W1f + (size_t)zn * KZ + l4 * 8;
                half8 xf[12], bx[12];
                ldA8(xb, xf[0], xf[1], xf[2], xf[3], xf[4], xf[5], xf[6], xf[7]);
                ldA4(xb + 256, xf[8], xf[9], xf[10], xf[11]);
                ldC8(wb, bx[0], bx[1], bx[2], bx[3], bx[4], bx[5], bx[6], bx[7]);
                ldC4(wb + 256, bx[8], bx[9], bx[10], bx[11]);
                WAITVM(0);
                #pragma unroll
                for (int j = 0; j < 12; ++j)
                    accZ = __builtin_amdgcn_mfma_f32_16x16x32_f16(xf[j], bx[j], accZ, 0, 0, 0);
            }

            gemm512B_sw(h0_t + rt * RTBLK, Bst, acc1, wid, lane,
                        semh0, rt, (unsigned)(t + 1));        // + h0(t) @ W1ih
            float hv[4];
            #pragma unroll
            for (int r = 0; r < 4; ++r) {
                const float gi = acc1[0][r] + gbi, gf = acc1[1][r] + gbf;
                const float gg = acc1[2][r] + gbg, go = acc1[3][r] + gbo;
                const float cn = sigm(gf) * creg[r] + sigm(gi) * tanhx(gg);
                creg[r] = cn;
                hv[r] = sigm(go) * tanhx(cn);
            }
            bounce_out(hv, h1_t + (rt * 32 + ct) * 1024);
            signal_slot(semh1, lwg, (unsigned)(t + 1));

            // preload z h-part weights while h1 stragglers finish
            half8 bh[16];
            #pragma unroll
            for (int j = 0; j < 16; ++j)
                bh[j] = *(const half8*)&W1f[(size_t)zn * KZ + DX + j * 32 + l4 * 8];

            if (t + 1 < NT) {   // z(t+1) h-part with split-wait on h1 producers
                const half_t* a0 = h1_t + rt * RTBLK + (l4 >> 1) * 1024 + zlrow * 16 + (l4 & 1) * 8;
                half8 hf[16];
                wait_rt_part(semh1, rt, (unsigned)(t + 1), 0, 16);
                #pragma unroll
                for (int j = 0; j < 8; ++j) ldA1(a0 + j * 2048, hf[j]);
                wait_rt_part(semh1, rt, (unsigned)(t + 1), 16, 32);
                #pragma unroll
                for (int j = 8; j < 16; ++j) ldA1(a0 + j * 2048, hf[j]);
                WAITVM(8);
                #pragma unroll
                for (int j = 0; j < 8; ++j)
                    accZ = __builtin_amdgcn_mfma_f32_16x16x32_f16(hf[j], bh[j], accZ, 0, 0, 0);
                WAITVM(0);
                #pragma unroll
                for (int j = 8; j < 16; ++j)
                    accZ = __builtin_amdgcn_mfma_f32_16x16x32_f16(hf[j], bh[j], accZ, 0, 0, 0);
                float zv[4];
                #pragma unroll
                for (int r = 0; r < 4; ++r) zv[r] = fmaxf(accZ[r] + zb1f, 0.f);
                bounce_out(zv, z_n + (zr * 32 + zc) * 1024);
                signal_slot(semz, lwg, (unsigned)(t + 2));
            }
        }
    }
}

// ---------------------------------------------------------------------------

extern "C" void kernel_launch(void* const* d_in, const int* in_sizes, int n_in,
                              void* d_out, int out_size, void* d_ws, size_t ws_size,
                              hipStream_t stream) {
    const float* x    = (const float*)d_in[0];
    const float* w1   = (const float*)d_in[1];
    const float* b1   = (const float*)d_in[2];
    const float* w_ih = (const float*)d_in[3];
    const float* w_hh = (const float*)d_in[4];
    const float* b_ih = (const float*)d_in[5];
    const float* b_hh = (const float*)d_in[6];
    const float* w2   = (const float*)d_in[7];
    const float* b2   = (const float*)d_in[8];
    float* out = (float*)d_out;
    (void)in_sizes; (void)n_in; (void)out_size; (void)ws_size;

    char* ws = (char*)d_ws;
    size_t off = 0;
    auto take = [&](size_t bytes) -> char* {
        char* p = ws + off;
        off += (bytes + 255) & ~(size_t)255;
        return p;
    };
    half_t* W1h  = (half_t*)take((size_t)512 * 512 * 2);
    half_t* W2h  = (half_t*)take((size_t)128 * 512 * 2);
    half_t* W1f  = (half_t*)take((size_t)512 * KZ * 2);
    half_t* Wl0p = (half_t*)take((size_t)NG * 1024 * 2);   // [ih 2MB | hh 2MB]
    half_t* Wl1p = (half_t*)take((size_t)NG * 1024 * 2);
    float*  b1f  = (float*)take((size_t)512 * 4);
    float*  bP0  = (float*)take((size_t)NG * 4);
    float*  bP1  = (float*)take((size_t)NG * 4);
    half_t* zbuf  = (half_t*)take((size_t)2 * NB * DH * 2);
    half_t* h0buf = (half_t*)take((size_t)2 * NB * DH * 2);
    half_t* h1buf = (half_t*)take((size_t)2 * NB * DH * 2);
    half_t* xhst  = (half_t*)take((size_t)2 * NB * DIN * 2);
    unsigned* semz  = (unsigned*)take((size_t)128 * 16 * 4);
    unsigned* semh0 = (unsigned*)take((size_t)128 * 16 * 4);
    unsigned* semh1 = (unsigned*)take((size_t)128 * 16 * 4);
    unsigned* semxh = (unsigned*)take((size_t)64 * 16 * 4);

    cvt_f32_f16<<<256, 256, 0, stream>>>(w1, W1h, 512 * 512);
    cvt_f32_f16<<<64, 256, 0, stream>>>(w2, W2h, 128 * 512);
    fold_w1<<<512, 256, 0, stream>>>(w1, w2, b1, b2, W1f, b1f);
    pack512<<<512, 256, 0, stream>>>(w_ih, Wl0p);
    pack512<<<512, 256, 0, stream>>>(w_hh, Wl0p + 1048576);
    pack512<<<512, 256, 0, stream>>>(w_ih + (size_t)NG * DH, Wl1p);
    pack512<<<512, 256, 0, stream>>>(w_hh + (size_t)NG * DH, Wl1p + 1048576);
    pack_bias<<<8, 256, 0, stream>>>(b_ih, b_hh, bP0);
    pack_bias<<<8, 256, 0, stream>>>(b_ih + NG, b_hh + NG, bP1);
    init_all<<<8, 256, 0, stream>>>(semz, (3 * 128 + 64) * 16);

    hipFuncSetAttribute((const void*)rnn_persistent,
                        hipFuncAttributeMaxDynamicSharedMemorySize, SMEM);

    void* args[] = { (void*)&x, (void*)&W1h, (void*)&W1f, (void*)&b1, (void*)&b1f,
                     (void*)&Wl0p, (void*)&bP0, (void*)&Wl1p, (void*)&bP1,
                     (void*)&W2h, (void*)&b2, (void*)&zbuf, (void*)&h0buf,
                     (void*)&h1buf, (void*)&xhst, (void*)&out,
                     (void*)&semz, (void*)&semh0, (void*)&semh1, (void*)&semxh };
    hipError_t e = hipLaunchCooperativeKernel((void*)rnn_persistent, dim3(NWG), dim3(256),
                                              args, SMEM, stream);
    if (e != hipSuccess) {
        rnn_persistent<<<dim3(NWG), dim3(256), SMEM, stream>>>(
            x, W1h, W1f, b1, b1f, Wl0p, bP0, Wl1p, bP1, W2h, b2,
            zbuf, h0buf, h1buf, xhst, out, semz, semh0, semh1, semxh);
    }
}